// Round 7
// baseline (24886.058 us; speedup 1.0000x reference)
//
#include <hip/hip_runtime.h>
#include <math.h>

#define T_STEPS 16384
#define IN_DIM  14
#define H_DIM   100
#define G_DIM   300   // 3*H

typedef float f2v __attribute__((ext_vector_type(2)));

#define REP25(M) M(0) M(1) M(2) M(3) M(4) M(5) M(6) M(7) M(8) M(9) M(10) M(11) \
                 M(12) M(13) M(14) M(15) M(16) M(17) M(18) M(19) M(20) M(21) M(22) M(23) M(24)

// ws float-index layout:
//  [0] flag1  [32] flag_g  [64] cons1  [96] cons_g   (ints, separate lines)
//  [1024 .. +8192)  ring1  : 64 slots x 128  (h1 stream, WG0 -> WG1)
//  [9216 .. +20480) ring_g : 64 slots x 320  (gi1 stream, WG1 -> WG2)
//  [32768 .. +T*300) gi0
#define RING1_OFS 1024
#define RINGG_OFS 9216
#define GI0_OFS   32768

#define AGENT __HIP_MEMORY_SCOPE_AGENT

// ---------------- Phase 0: gi0 = x @ w_ih0^T + b_ih0 ----------------
__global__ void gi0_kernel(const float* __restrict__ x,
                           const float* __restrict__ w_ih0,
                           const float* __restrict__ b_ih0,
                           float* __restrict__ gi0) {
    int e = blockIdx.x * blockDim.x + threadIdx.x;
    if (e >= T_STEPS * G_DIM) return;
    int t = e / G_DIM;
    int j = e - t * G_DIM;
    const float* xr = x + t * IN_DIM;
    const float* wr = w_ih0 + j * IN_DIM;
    float acc = b_ih0[j];
    #pragma unroll
    for (int k = 0; k < IN_DIM; ++k) acc = fmaf(xr[k], wr[k], acc);
    gi0[e] = acc;
}

// ---------------- Phase 1: 3-WG pipelined GRU ----------------
// HISTORY (do not regress): compiler VGPR budget ~ 1024/WG-waves (8w->128,
// 15w->64; R1-R6). >budget weights => scratch spill => 10 GB HBM/step => 15-24ms.
// 90K weight floats can NEVER fit one CU's grant (max ~65K). Hence 3 WGs,
// 320 thr (5 waves) each, 1 row/thread = 100 weight VGPRs < 128 cap.
__global__ __attribute__((amdgpu_flat_work_group_size(320, 320)))
void gru3_kernel(const float* __restrict__ gi0,
                 float* __restrict__ ws,
                 const float* __restrict__ w_hh0, const float* __restrict__ b_hh0,
                 const float* __restrict__ w_ih1, const float* __restrict__ b_ih1,
                 const float* __restrict__ w_hh1, const float* __restrict__ b_hh1,
                 const float* __restrict__ fc_w,  const float* __restrict__ fc_b,
                 float* __restrict__ out) {
    __shared__ __align__(16) float hvec[128];
    __shared__ float gh[G_DIM];

    const int tid = threadIdx.x;
    const int bid = blockIdx.x;
    const bool act = tid < G_DIM;
    const int row = act ? tid : (G_DIM - 1);

    int* flag1 = (int*)(ws + 0);
    int* flagg = (int*)(ws + 32);
    int* cons1 = (int*)(ws + 64);
    int* consg = (int*)(ws + 96);
    float* ring1 = ws + RING1_OFS;
    float* ringg = ws + RINGG_OFS;

    const float* wmat; const float* bvec;
    if (bid == 0)      { wmat = w_hh0; bvec = b_hh0; }
    else if (bid == 1) { wmat = w_ih1; bvec = b_ih1; }
    else               { wmat = w_hh1; bvec = b_hh1; }
    const float bias = bvec[row];

    // 25 float4-pairs of weights = 100 VGPRs, named + pinned (anti-remat/spill)
    #define DW(k) f2v wA_##k, wB_##k;
    REP25(DW)
    #undef DW
    {
        const float4* wp = (const float4*)(wmat + (size_t)row * H_DIM);
        #define LW(k) { float4 A = wp[k]; wA_##k.x = A.x; wA_##k.y = A.y; wB_##k.x = A.z; wB_##k.y = A.w; }
        REP25(LW)
        #undef LW
    }
    #define PW(k) asm volatile("" : "+v"(wA_##k), "+v"(wB_##k));
    REP25(PW)
    #undef PW

    if (tid < 128) hvec[tid] = 0.0f;   // h1[-1] / h2[-1] = 0
    __syncthreads();

    #define DOTK(k) { float4 V = hv4[k]; \
                      f2v va; va.x = V.x; va.y = V.y; accA += wA_##k * va; \
                      f2v vb; vb.x = V.z; vb.y = V.w; accB += wB_##k * vb; }

    if (bid == 0) {
        // ---- layer-0 recurrence (self-loop, local LDS) ----
        float hp = 0.0f;
        for (int i = 0; i < T_STEPS; ++i) {
            if ((i & 15) == 0 && i >= 64) {   // back-pressure on ring1
                if (tid == 0) {
                    while (__hip_atomic_load(cons1, __ATOMIC_ACQUIRE, AGENT) < i - 40) {}
                }
                __syncthreads();
            }
            float gr = 0.f, gz = 0.f, gn = 0.f;
            if (tid < H_DIM) {
                const float* p = gi0 + (size_t)i * G_DIM + tid;
                gr = p[0]; gz = p[H_DIM]; gn = p[2 * H_DIM];
            }
            const float4* hv4 = (const float4*)hvec;
            f2v accA, accB; accA.x = bias; accA.y = 0.f; accB.x = 0.f; accB.y = 0.f;
            REP25(DOTK)
            if (act) gh[tid] = (accA.x + accA.y) + (accB.x + accB.y);
            __syncthreads();
            if (tid < H_DIM) {
                float r = 1.0f / (1.0f + expf(-(gr + gh[tid])));
                float z = 1.0f / (1.0f + expf(-(gz + gh[H_DIM + tid])));
                float n = tanhf(gn + r * gh[2 * H_DIM + tid]);
                float hn = (1.0f - z) * n + z * hp;
                hp = hn;
                hvec[tid] = hn;
                __hip_atomic_store(ring1 + ((i & 63) << 7) + tid, hn, __ATOMIC_RELAXED, AGENT);
            }
            __syncthreads();   // drains vmcnt: ring stores done before flag
            if (tid == 0) __hip_atomic_store(flag1, i + 1, __ATOMIC_RELEASE, AGENT);
        }
    } else if (bid == 1) {
        // ---- layer-1 input projection (feed-forward, trails WG0) ----
        int seen = 0;
        for (int i = 0; i < T_STEPS; ++i) {
            if (tid == 0) {
                if ((i & 15) == 0 && i >= 64) {   // back-pressure on ring_g
                    while (__hip_atomic_load(consg, __ATOMIC_ACQUIRE, AGENT) < i - 40) {}
                }
                if (seen < i + 1) {
                    int f;
                    do { f = __hip_atomic_load(flag1, __ATOMIC_ACQUIRE, AGENT); } while (f < i + 1);
                    seen = f;
                }
            }
            __syncthreads();
            if (tid < H_DIM) {
                float v = __hip_atomic_load(ring1 + ((i & 63) << 7) + tid, __ATOMIC_RELAXED, AGENT);
                hvec[tid] = v;
            }
            __syncthreads();
            const float4* hv4 = (const float4*)hvec;
            f2v accA, accB; accA.x = bias; accA.y = 0.f; accB.x = 0.f; accB.y = 0.f;
            REP25(DOTK)
            if (act) {
                float v = (accA.x + accA.y) + (accB.x + accB.y);
                __hip_atomic_store(ringg + (i & 63) * 320 + tid, v, __ATOMIC_RELAXED, AGENT);
            }
            __syncthreads();   // drains vmcnt
            if (tid == 0) {
                __hip_atomic_store(flagg, i + 1, __ATOMIC_RELEASE, AGENT);
                if ((i & 15) == 15) __hip_atomic_store(cons1, i + 1, __ATOMIC_RELAXED, AGENT);
            }
        }
    } else {
        // ---- layer-1 recurrence (self-loop) + FC epilogue ----
        float hp = 0.0f; int seen = 0;
        for (int i = 0; i < T_STEPS; ++i) {
            if (tid == 0 && seen < i + 1) {
                int f;
                do { f = __hip_atomic_load(flagg, __ATOMIC_ACQUIRE, AGENT); } while (f < i + 1);
                seen = f;
            }
            __syncthreads();
            // issue gi1 loads early; latency overlaps the dot below
            float gr = 0.f, gz = 0.f, gn = 0.f;
            if (tid < H_DIM) {
                const float* p = ringg + (i & 63) * 320;
                gr = __hip_atomic_load(p + tid,            __ATOMIC_RELAXED, AGENT);
                gz = __hip_atomic_load(p + H_DIM + tid,    __ATOMIC_RELAXED, AGENT);
                gn = __hip_atomic_load(p + 2 * H_DIM + tid,__ATOMIC_RELAXED, AGENT);
            }
            const float4* hv4 = (const float4*)hvec;
            f2v accA, accB; accA.x = bias; accA.y = 0.f; accB.x = 0.f; accB.y = 0.f;
            REP25(DOTK)
            if (act) gh[tid] = (accA.x + accA.y) + (accB.x + accB.y);
            __syncthreads();
            if (tid < H_DIM) {
                float r = 1.0f / (1.0f + expf(-(gr + gh[tid])));
                float z = 1.0f / (1.0f + expf(-(gz + gh[H_DIM + tid])));
                float n = tanhf(gn + r * gh[2 * H_DIM + tid]);
                float hn = (1.0f - z) * n + z * hp;
                hp = hn;
                hvec[tid] = hn;
            }
            if (tid == 0 && (i & 15) == 15)
                __hip_atomic_store(consg, i + 1, __ATOMIC_RELAXED, AGENT);
            __syncthreads();
        }
        // FC: out = fc_b + fc_w . h2[T-1]
        if (tid < 64) {
            float s = 0.0f;
            for (int j = tid; j < H_DIM; j += 64) s = fmaf(fc_w[j], hvec[j], s);
            #pragma unroll
            for (int off = 32; off > 0; off >>= 1) s += __shfl_down(s, off);
            if (tid == 0) out[0] = s + fc_b[0];
        }
    }
    #undef DOTK
}

extern "C" void kernel_launch(void* const* d_in, const int* in_sizes, int n_in,
                              void* d_out, int out_size, void* d_ws, size_t ws_size,
                              hipStream_t stream) {
    const float* x     = (const float*)d_in[0];
    const float* w_ih0 = (const float*)d_in[1];
    const float* w_hh0 = (const float*)d_in[2];
    const float* b_ih0 = (const float*)d_in[3];
    const float* b_hh0 = (const float*)d_in[4];
    const float* w_ih1 = (const float*)d_in[5];
    const float* w_hh1 = (const float*)d_in[6];
    const float* b_ih1 = (const float*)d_in[7];
    const float* b_hh1 = (const float*)d_in[8];
    const float* fc_w  = (const float*)d_in[9];
    const float* fc_b  = (const float*)d_in[10];
    float* out = (float*)d_out;

    float* ws  = (float*)d_ws;
    float* gi0 = ws + GI0_OFS;

    const int total = T_STEPS * G_DIM;
    gi0_kernel<<<(total + 255) / 256, 256, 0, stream>>>(x, w_ih0, b_ih0, gi0);
    gru3_kernel<<<3, 320, 0, stream>>>(gi0, ws,
                                       w_hh0, b_hh0, w_ih1, b_ih1,
                                       w_hh1, b_hh1, fc_w, fc_b, out);
}

// Round 8
// 19225.555 us; speedup vs baseline: 1.2944x; 1.2944x over previous
//
#include <hip/hip_runtime.h>
#include <math.h>

#define T_STEPS 16384
#define IN_DIM  14
#define H_DIM   100
#define G_DIM   300   // 3*H

typedef float f2v __attribute__((ext_vector_type(2)));

#define REP25(M) M(0) M(1) M(2) M(3) M(4) M(5) M(6) M(7) M(8) M(9) M(10) M(11) \
                 M(12) M(13) M(14) M(15) M(16) M(17) M(18) M(19) M(20) M(21) M(22) M(23) M(24)

// ws float-index layout:
//  [0] flag1  [32] flag_g  [64] cons1  [96] cons_g   (ints, separate lines)
//  [1024 .. +8192)  ring1  : 64 slots x 128  (h1 stream, WG0 -> WG1)
//  [9216 .. +20480) ring_g : 64 slots x 320  (gi1 stream, WG1 -> WG2)
//  [32768 .. +T*300) gi0
#define RING1_OFS 1024
#define RINGG_OFS 9216
#define GI0_OFS   32768

#define AGENT __HIP_MEMORY_SCOPE_AGENT

// ---------------- Phase 0: gi0 = x @ w_ih0^T + b_ih0 ----------------
__global__ void gi0_kernel(const float* __restrict__ x,
                           const float* __restrict__ w_ih0,
                           const float* __restrict__ b_ih0,
                           float* __restrict__ gi0) {
    int e = blockIdx.x * blockDim.x + threadIdx.x;
    if (e >= T_STEPS * G_DIM) return;
    int t = e / G_DIM;
    int j = e - t * G_DIM;
    const float* xr = x + t * IN_DIM;
    const float* wr = w_ih0 + j * IN_DIM;
    float acc = b_ih0[j];
    #pragma unroll
    for (int k = 0; k < IN_DIM; ++k) acc = fmaf(xr[k], wr[k], acc);
    gi0[e] = acc;
}

// ---------------- Phase 1: 3-WG pipelined GRU ----------------
// HISTORY (do not regress): compiler VGPR budget = 256 / targeted-waves-per-EU.
//  R1 (lb 960,4): 64.  R2/R4 (2/EU): 128.  R5 ((1)->clamp 2): 128.
//  R6 ((4)): 64.  R7 (NO attribute -> default ~4/EU): 64, FETCH+WRITE 53 GB.
//  => MUST declare amdgpu_waves_per_eu(2,2): 5-wave WG, 2/EU feasible, grants
//  128 regs; this kernel asks ~115 (100 pinned weights + scratch). Any config
//  whose ask exceeds the grant spills to HBM scratch (10-53 GB => 15-25 ms).
__global__ __attribute__((amdgpu_flat_work_group_size(320, 320), amdgpu_waves_per_eu(2, 2)))
void gru3_kernel(const float* __restrict__ gi0,
                 float* __restrict__ ws,
                 const float* __restrict__ w_hh0, const float* __restrict__ b_hh0,
                 const float* __restrict__ w_ih1, const float* __restrict__ b_ih1,
                 const float* __restrict__ w_hh1, const float* __restrict__ b_hh1,
                 const float* __restrict__ fc_w,  const float* __restrict__ fc_b,
                 float* __restrict__ out) {
    __shared__ __align__(16) float hvec[128];
    __shared__ float gh[G_DIM];

    const int tid = threadIdx.x;
    const int bid = blockIdx.x;
    const bool act = tid < G_DIM;
    const int row = act ? tid : (G_DIM - 1);

    int* flag1 = (int*)(ws + 0);
    int* flagg = (int*)(ws + 32);
    int* cons1 = (int*)(ws + 64);
    int* consg = (int*)(ws + 96);
    float* ring1 = ws + RING1_OFS;
    float* ringg = ws + RINGG_OFS;

    const float* wmat; const float* bvec;
    if (bid == 0)      { wmat = w_hh0; bvec = b_hh0; }
    else if (bid == 1) { wmat = w_ih1; bvec = b_ih1; }
    else               { wmat = w_hh1; bvec = b_hh1; }
    const float bias = bvec[row];

    // 25 float4-pairs of weights = 100 VGPRs, named + pinned (anti-remat/spill)
    #define DW(k) f2v wA_##k, wB_##k;
    REP25(DW)
    #undef DW
    {
        const float4* wp = (const float4*)(wmat + (size_t)row * H_DIM);
        #define LW(k) { float4 A = wp[k]; wA_##k.x = A.x; wA_##k.y = A.y; wB_##k.x = A.z; wB_##k.y = A.w; }
        REP25(LW)
        #undef LW
    }
    #define PW(k) asm volatile("" : "+v"(wA_##k), "+v"(wB_##k));
    REP25(PW)
    #undef PW

    if (tid < 128) hvec[tid] = 0.0f;   // h1[-1] / h2[-1] = 0
    __syncthreads();

    #define DOTK(k) { float4 V = hv4[k]; \
                      f2v va; va.x = V.x; va.y = V.y; accA += wA_##k * va; \
                      f2v vb; vb.x = V.z; vb.y = V.w; accB += wB_##k * vb; }

    if (bid == 0) {
        // ---- layer-0 recurrence (self-loop, local LDS) ----
        float hp = 0.0f;
        for (int i = 0; i < T_STEPS; ++i) {
            if ((i & 15) == 0 && i >= 64) {   // back-pressure on ring1
                if (tid == 0) {
                    while (__hip_atomic_load(cons1, __ATOMIC_ACQUIRE, AGENT) < i - 40) {}
                }
                __syncthreads();
            }
            float gr = 0.f, gz = 0.f, gn = 0.f;
            if (tid < H_DIM) {
                const float* p = gi0 + (size_t)i * G_DIM + tid;
                gr = p[0]; gz = p[H_DIM]; gn = p[2 * H_DIM];
            }
            const float4* hv4 = (const float4*)hvec;
            f2v accA, accB; accA.x = bias; accA.y = 0.f; accB.x = 0.f; accB.y = 0.f;
            REP25(DOTK)
            if (act) gh[tid] = (accA.x + accA.y) + (accB.x + accB.y);
            __syncthreads();
            if (tid < H_DIM) {
                float r = 1.0f / (1.0f + expf(-(gr + gh[tid])));
                float z = 1.0f / (1.0f + expf(-(gz + gh[H_DIM + tid])));
                float n = tanhf(gn + r * gh[2 * H_DIM + tid]);
                float hn = (1.0f - z) * n + z * hp;
                hp = hn;
                hvec[tid] = hn;
                __hip_atomic_store(ring1 + ((i & 63) << 7) + tid, hn, __ATOMIC_RELAXED, AGENT);
            }
            __syncthreads();   // drains vmcnt: ring stores done before flag
            if (tid == 0) __hip_atomic_store(flag1, i + 1, __ATOMIC_RELEASE, AGENT);
        }
    } else if (bid == 1) {
        // ---- layer-1 input projection (feed-forward, trails WG0) ----
        int seen = 0;
        for (int i = 0; i < T_STEPS; ++i) {
            if (tid == 0) {
                if ((i & 15) == 0 && i >= 64) {   // back-pressure on ring_g
                    while (__hip_atomic_load(consg, __ATOMIC_ACQUIRE, AGENT) < i - 40) {}
                }
                if (seen < i + 1) {
                    int f;
                    do { f = __hip_atomic_load(flag1, __ATOMIC_ACQUIRE, AGENT); } while (f < i + 1);
                    seen = f;
                }
            }
            __syncthreads();
            if (tid < H_DIM) {
                float v = __hip_atomic_load(ring1 + ((i & 63) << 7) + tid, __ATOMIC_RELAXED, AGENT);
                hvec[tid] = v;
            }
            __syncthreads();
            const float4* hv4 = (const float4*)hvec;
            f2v accA, accB; accA.x = bias; accA.y = 0.f; accB.x = 0.f; accB.y = 0.f;
            REP25(DOTK)
            if (act) {
                float v = (accA.x + accA.y) + (accB.x + accB.y);
                __hip_atomic_store(ringg + (i & 63) * 320 + tid, v, __ATOMIC_RELAXED, AGENT);
            }
            __syncthreads();   // drains vmcnt
            if (tid == 0) {
                __hip_atomic_store(flagg, i + 1, __ATOMIC_RELEASE, AGENT);
                if ((i & 15) == 15) __hip_atomic_store(cons1, i + 1, __ATOMIC_RELAXED, AGENT);
            }
        }
    } else {
        // ---- layer-1 recurrence (self-loop) + FC epilogue ----
        float hp = 0.0f; int seen = 0;
        for (int i = 0; i < T_STEPS; ++i) {
            if (tid == 0 && seen < i + 1) {
                int f;
                do { f = __hip_atomic_load(flagg, __ATOMIC_ACQUIRE, AGENT); } while (f < i + 1);
                seen = f;
            }
            __syncthreads();
            // issue gi1 loads early; latency overlaps the dot below
            float gr = 0.f, gz = 0.f, gn = 0.f;
            if (tid < H_DIM) {
                const float* p = ringg + (i & 63) * 320;
                gr = __hip_atomic_load(p + tid,            __ATOMIC_RELAXED, AGENT);
                gz = __hip_atomic_load(p + H_DIM + tid,    __ATOMIC_RELAXED, AGENT);
                gn = __hip_atomic_load(p + 2 * H_DIM + tid,__ATOMIC_RELAXED, AGENT);
            }
            const float4* hv4 = (const float4*)hvec;
            f2v accA, accB; accA.x = bias; accA.y = 0.f; accB.x = 0.f; accB.y = 0.f;
            REP25(DOTK)
            if (act) gh[tid] = (accA.x + accA.y) + (accB.x + accB.y);
            __syncthreads();
            if (tid < H_DIM) {
                float r = 1.0f / (1.0f + expf(-(gr + gh[tid])));
                float z = 1.0f / (1.0f + expf(-(gz + gh[H_DIM + tid])));
                float n = tanhf(gn + r * gh[2 * H_DIM + tid]);
                float hn = (1.0f - z) * n + z * hp;
                hp = hn;
                hvec[tid] = hn;
            }
            if (tid == 0 && (i & 15) == 15)
                __hip_atomic_store(consg, i + 1, __ATOMIC_RELAXED, AGENT);
            __syncthreads();
        }
        // FC: out = fc_b + fc_w . h2[T-1]
        if (tid < 64) {
            float s = 0.0f;
            for (int j = tid; j < H_DIM; j += 64) s = fmaf(fc_w[j], hvec[j], s);
            #pragma unroll
            for (int off = 32; off > 0; off >>= 1) s += __shfl_down(s, off);
            if (tid == 0) out[0] = s + fc_b[0];
        }
    }
    #undef DOTK
}

extern "C" void kernel_launch(void* const* d_in, const int* in_sizes, int n_in,
                              void* d_out, int out_size, void* d_ws, size_t ws_size,
                              hipStream_t stream) {
    const float* x     = (const float*)d_in[0];
    const float* w_ih0 = (const float*)d_in[1];
    const float* w_hh0 = (const float*)d_in[2];
    const float* b_ih0 = (const float*)d_in[3];
    const float* b_hh0 = (const float*)d_in[4];
    const float* w_ih1 = (const float*)d_in[5];
    const float* w_hh1 = (const float*)d_in[6];
    const float* b_ih1 = (const float*)d_in[7];
    const float* b_hh1 = (const float*)d_in[8];
    const float* fc_w  = (const float*)d_in[9];
    const float* fc_b  = (const float*)d_in[10];
    float* out = (float*)d_out;

    float* ws  = (float*)d_ws;
    float* gi0 = ws + GI0_OFS;

    const int total = T_STEPS * G_DIM;
    gi0_kernel<<<(total + 255) / 256, 256, 0, stream>>>(x, w_ih0, b_ih0, gi0);
    gru3_kernel<<<3, 320, 0, stream>>>(gi0, ws,
                                       w_hh0, b_hh0, w_ih1, b_ih1,
                                       w_hh1, b_hh1, fc_w, fc_b, out);
}